// Round 15
// baseline (165.356 us; speedup 1.0000x reference)
//
#include <hip/hip_runtime.h>
#include <math.h>

#define LSEQ 2048
#define DMODEL 768
#define NHEAD 12
#define DHEAD 64
#define NCHUNK 32   // 2048 / 64
#define NMERGED 5376   // 2304 qkv | 1536(hole: V->vb) | sem_amp sem_phase ctx_amp ctx_phase

typedef unsigned short ushort_t;
typedef __attribute__((ext_vector_type(8))) short short8;
typedef float float4v __attribute__((ext_vector_type(4)));

__device__ __forceinline__ ushort_t f2b(float f) {
    union { float f; unsigned int u; } v; v.f = f;
    unsigned int u = v.u;
    return (ushort_t)((u + 0x7fffu + ((u >> 16) & 1u)) >> 16);
}
__device__ __forceinline__ float b2f(ushort_t u) {
    union { unsigned int u; float f; } v; v.u = ((unsigned int)u) << 16;
    return v.f;
}

// async 16B global->LDS (wave-uniform LDS base + lane*16)
__device__ __forceinline__ void gl_lds16(const ushort_t* g, ushort_t* l) {
    __builtin_amdgcn_global_load_lds(
        (const __attribute__((address_space(1))) unsigned int*)g,
        (__attribute__((address_space(3))) unsigned int*)l, 16, 0, 0);
}

// ---------------- fused pre-pass: LN(+x cast) for blocks <2048, weight transpose after ----------------
__global__ void pre_kernel(const float* __restrict__ x, const float* __restrict__ g,
                           const float* __restrict__ beta, ushort_t* __restrict__ xn,
                           ushort_t* __restrict__ xb,
                           const float* __restrict__ Wq, const float* __restrict__ Ws,
                           const float* __restrict__ Wc, ushort_t* __restrict__ Tm,
                           const float* __restrict__ Wp, ushort_t* __restrict__ Tp) {
    __shared__ float red[4];
    __shared__ float bc;
    __shared__ float tile[32][33];
    int tid = threadIdx.x;
    if (blockIdx.x < 2048) {
        int row = blockIdx.x;
        const float* xr = x + (size_t)row * DMODEL;
        float v0 = xr[tid], v1 = xr[tid + 256], v2 = xr[tid + 512];
        float s = v0 + v1 + v2;
#pragma unroll
        for (int o = 32; o > 0; o >>= 1) s += __shfl_down(s, o);
        if ((tid & 63) == 0) red[tid >> 6] = s;
        __syncthreads();
        if (tid == 0) bc = (red[0] + red[1] + red[2] + red[3]) * (1.0f / DMODEL);
        __syncthreads();
        float mu = bc;
        float d0 = v0 - mu, d1 = v1 - mu, d2 = v2 - mu;
        float vs = d0 * d0 + d1 * d1 + d2 * d2;
        __syncthreads();
#pragma unroll
        for (int o = 32; o > 0; o >>= 1) vs += __shfl_down(vs, o);
        if ((tid & 63) == 0) red[tid >> 6] = vs;
        __syncthreads();
        if (tid == 0) bc = rsqrtf((red[0] + red[1] + red[2] + red[3]) * (1.0f / DMODEL) + 1e-5f);
        __syncthreads();
        float r = bc;
        ushort_t* xo = xn + (size_t)row * DMODEL;
        ushort_t* xc = xb + (size_t)row * DMODEL;
        xo[tid]       = f2b(d0 * r * g[tid]       + beta[tid]);
        xo[tid + 256] = f2b(d1 * r * g[tid + 256] + beta[tid + 256]);
        xo[tid + 512] = f2b(d2 * r * g[tid + 512] + beta[tid + 512]);
        xc[tid]       = f2b(v0);
        xc[tid + 256] = f2b(v1);
        xc[tid + 512] = f2b(v2);
    } else {
        int bid = blockIdx.x - 2048;          // 0..6911 = 72*24*4
        int nb = bid % 72;
        int kb = (bid / 72) % 24;
        int zb = bid / (72 * 24);
        const float* W; ushort_t* Wt; int N;
        switch (zb) {
            case 0: W = Wq; Wt = Tm;                        N = 2304; break;
            case 1: W = Ws; Wt = Tm + (size_t)2304 * 768;   N = 1536; break;
            case 2: W = Wc; Wt = Tm + (size_t)3840 * 768;   N = 1536; break;
            default: W = Wp; Wt = Tp;                       N = 768;  break;
        }
        int nbase = nb * 32;
        if (nbase >= N) return;
        int tr = tid >> 5, tc = tid & 31;
        int kbase = kb * 32;
#pragma unroll
        for (int p = 0; p < 4; p++) {
            int r = p * 8 + tr;
            tile[r][tc] = W[(size_t)(kbase + r) * N + nbase + tc];
        }
        __syncthreads();
#pragma unroll
        for (int p = 0; p < 4; p++) {
            int r = p * 8 + tr;
            Wt[(size_t)(nbase + r) * 768 + kbase + tc] = f2b(tile[tc][r]);
        }
    }
}

// ---------------- merged bf16 MFMA GEMM: BK=32 single-buffer, swizzled LDS, XCD-banded grid,
//                  LDS-staged coalesced bf16 epilogue (R12 proven) ----------------
__global__ __launch_bounds__(256) void gemm_merged_kernel(
    const ushort_t* __restrict__ Axn, const ushort_t* __restrict__ Axb,
    const ushort_t* __restrict__ Bt,
    const float* __restrict__ b_qkv, const float* __restrict__ b_sem,
    const float* __restrict__ b_ctx, ushort_t* __restrict__ Cb,
    ushort_t* __restrict__ vb) {
    const int K = 768;
    __shared__ ushort_t As[128 * 32];
    __shared__ ushort_t Bs[128 * 32];
    __shared__ ushort_t Ct[128 * 132];   // padded stride: coalescing stage for C
    int tid = threadIdx.x;
    int wave = tid >> 6, lane = tid & 63;
    int wm = (wave >> 1) * 64, wn = (wave & 1) * 64;
    int quad = lane >> 4, l16 = lane & 15;
    int bid = blockIdx.x;                 // 0..671
    int xcd = bid & 7, slot = bid >> 3;   // 84 slots per XCD
    int tile_id = xcd * 84 + slot;
    int m0 = (tile_id & 15) * 128;        // m fastest: 16 consecutive slots share one B tile
    int n0 = (tile_id >> 4) * 128;
    const ushort_t* A = (n0 < 2304) ? Axn : Axb;
    const float* bias = (n0 < 2304) ? (b_qkv + n0) : (n0 < 3840 ? (b_sem + n0 - 2304) : (b_ctx + n0 - 3840));

    int r0 = tid >> 2;                                  // row 0..63 (both 64-row halves)
    int kc = ((tid & 3) ^ ((r0 >> 1) & 3)) * 8;         // swizzled global k-chunk
    const ushort_t* Ag0 = A + (size_t)(m0 + r0) * K + kc;
    const ushort_t* Ag1 = A + (size_t)(m0 + 64 + r0) * K + kc;
    const ushort_t* Bg0 = Bt + (size_t)(n0 + r0) * K + kc;
    const ushort_t* Bg1 = Bt + (size_t)(n0 + 64 + r0) * K + kc;
    ushort_t* Al0 = &As[(wave * 64) * 8];
    ushort_t* Al1 = &As[(256 + wave * 64) * 8];
    ushort_t* Bl0 = &Bs[(wave * 64) * 8];
    ushort_t* Bl1 = &Bs[(256 + wave * 64) * 8];

    float4v acc[4][4];
#pragma unroll
    for (int i = 0; i < 4; i++)
#pragma unroll
        for (int j = 0; j < 4; j++)
#pragma unroll
            for (int r = 0; r < 4; r++) acc[i][j][r] = 0.0f;

    for (int k0 = 0; k0 < K; k0 += 32) {
        gl_lds16(Ag0 + k0, Al0);
        gl_lds16(Ag1 + k0, Al1);
        gl_lds16(Bg0 + k0, Bl0);
        gl_lds16(Bg1 + k0, Bl1);
        __syncthreads();
        short8 af[4], bf[4];
#pragma unroll
        for (int i = 0; i < 4; i++) {
            int rr = wm + i * 16 + l16;
            af[i] = *(const short8*)&As[rr * 32 + ((quad ^ ((rr >> 1) & 3)) * 8)];
        }
#pragma unroll
        for (int j = 0; j < 4; j++) {
            int rr = wn + j * 16 + l16;
            bf[j] = *(const short8*)&Bs[rr * 32 + ((quad ^ ((rr >> 1) & 3)) * 8)];
        }
#pragma unroll
        for (int i = 0; i < 4; i++)
#pragma unroll
            for (int j = 0; j < 4; j++)
                acc[i][j] = __builtin_amdgcn_mfma_f32_16x16x32_bf16(af[i], bf[j], acc[i][j], 0, 0, 0);
        __syncthreads();
    }
    // epilogue: acc -> bf16 LDS tile, then coalesced 16B stores
#pragma unroll
    for (int i = 0; i < 4; i++) {
#pragma unroll
        for (int j = 0; j < 4; j++) {
            int colb = wn + j * 16 + l16;
            float bv = bias[colb];
#pragma unroll
            for (int r = 0; r < 4; r++) {
                int row = wm + i * 16 + quad * 4 + r;
                Ct[row * 132 + colb] = f2b(acc[i][j][r] + bv);
            }
        }
    }
    __syncthreads();
    bool is_v = (n0 >= 1536 && n0 < 2304);   // block-uniform
    int rr0 = tid >> 4;             // 0..15
    int cc0 = (tid & 15) * 8;       // 0..120
#pragma unroll
    for (int p = 0; p < 8; p++) {
        int r = p * 16 + rr0;
        uint4 vdat = *(const uint4*)&Ct[r * 132 + cc0];
        int grow = m0 + r;
        if (is_v) {
            *(uint4*)&vb[(size_t)grow * DMODEL + (n0 - 1536) + cc0] = vdat;
        } else {
            *(uint4*)&Cb[(size_t)grow * NMERGED + n0 + cc0] = vdat;
        }
    }
}

// ---------------- 64x64-tile bf16 MFMA GEMM, BK=32, swizzled (proj: N=768), fp32 out ----------------
__global__ __launch_bounds__(256) void gemm_64_kernel(
    const ushort_t* __restrict__ A, const ushort_t* __restrict__ Bt,
    const float* __restrict__ bias, float* __restrict__ C,
    int N, int K) {
    __shared__ ushort_t As[64 * 32];
    __shared__ ushort_t Bs[64 * 32];
    int tid = threadIdx.x;
    int wave = tid >> 6, lane = tid & 63;
    int wm = (wave >> 1) * 32, wn = (wave & 1) * 32;
    int quad = lane >> 4, l16 = lane & 15;
    int m0 = blockIdx.y * 64, n0 = blockIdx.x * 64;

    int r0 = tid >> 2;
    int kc = ((tid & 3) ^ ((r0 >> 1) & 3)) * 8;
    const ushort_t* Ag = A + (size_t)(m0 + r0) * K + kc;
    const ushort_t* Bg = Bt + (size_t)(n0 + r0) * K + kc;
    ushort_t* Al = &As[(wave * 16) * 32];
    ushort_t* Bl = &Bs[(wave * 16) * 32];

    float4v acc[2][2];
#pragma unroll
    for (int i = 0; i < 2; i++)
#pragma unroll
        for (int j = 0; j < 2; j++)
#pragma unroll
            for (int r = 0; r < 4; r++) acc[i][j][r] = 0.0f;

    for (int k0 = 0; k0 < K; k0 += 32) {
        gl_lds16(Ag + k0, Al);
        gl_lds16(Bg + k0, Bl);
        __syncthreads();
        short8 af[2], bf[2];
#pragma unroll
        for (int i = 0; i < 2; i++) {
            int rr = wm + i * 16 + l16;
            af[i] = *(const short8*)&As[rr * 32 + ((quad ^ ((rr >> 1) & 3)) * 8)];
        }
#pragma unroll
        for (int j = 0; j < 2; j++) {
            int rr = wn + j * 16 + l16;
            bf[j] = *(const short8*)&Bs[rr * 32 + ((quad ^ ((rr >> 1) & 3)) * 8)];
        }
#pragma unroll
        for (int i = 0; i < 2; i++)
#pragma unroll
            for (int j = 0; j < 2; j++)
                acc[i][j] = __builtin_amdgcn_mfma_f32_16x16x32_bf16(af[i], bf[j], acc[i][j], 0, 0, 0);
        __syncthreads();
    }
#pragma unroll
    for (int i = 0; i < 2; i++) {
#pragma unroll
        for (int j = 0; j < 2; j++) {
            int col = n0 + wn + j * 16 + l16;
            float bv = bias[col];
#pragma unroll
            for (int r = 0; r < 4; r++) {
                int row = m0 + wm + i * 16 + quad * 4 + r;
                C[(size_t)row * N + col] = acc[i][j][r] + bv;
            }
        }
    }
}

// ---------------- gate + feature map (bf16 in) -> bf16 qf/kf (4 elems/thread) ----------------
__device__ __forceinline__ float softplus_f(float x) {
    return (x > 15.f) ? x : log1pf(expf(x));
}

__global__ void gate_feat_kernel(const ushort_t* __restrict__ qscb,
                                 ushort_t* __restrict__ qf, ushort_t* __restrict__ kf) {
    int t = blockIdx.x * 256 + threadIdx.x;      // t < L*D/4 = 393216
    int l = t / 192, d = (t - l * 192) * 4;
    size_t base = (size_t)l * NMERGED;
    ushort_t sa[4], sp[4], ca[4], cp[4], q[4], k[4];
    *(uint2*)sa = *(const uint2*)&qscb[base + 2304 + d];
    *(uint2*)sp = *(const uint2*)&qscb[base + 3072 + d];
    *(uint2*)ca = *(const uint2*)&qscb[base + 3840 + d];
    *(uint2*)cp = *(const uint2*)&qscb[base + 4608 + d];
    *(uint2*)q  = *(const uint2*)&qscb[base + d];
    *(uint2*)k  = *(const uint2*)&qscb[base + 768 + d];
    ushort_t qo[4], ko[4];
#pragma unroll
    for (int j = 0; j < 4; j++) {
        float amp = softplus_f(b2f(sa[j])) * softplus_f(b2f(ca[j]));
        float tt = amp * cosf(b2f(sp[j]) - b2f(cp[j]));
        float gate = 1.0f / (1.0f + expf(-tt));
        float kv = b2f(k[j]) * gate;
        float qv = b2f(q[j]);
        qo[j] = f2b((qv > 0.f) ? qv + 1.0f : expf(qv));
        ko[j] = f2b((kv > 0.f) ? kv + 1.0f : expf(kv));
    }
    size_t o = (size_t)l * DMODEL + d;
    *(uint2*)&qf[o] = *(uint2*)qo;
    *(uint2*)&kf[o] = *(uint2*)ko;
}

// ---------------- per-(head,chunk) KV state sums via MFMA (R12 proven) ----------------
// S_t layout per (h,c): [e*64+d] = sum_l k[l][d]*v[l][e]; [4096+d] = ksum[d]
__global__ __launch_bounds__(256) void chunk_sum_mfma(const ushort_t* __restrict__ kf,
                                                      const ushort_t* __restrict__ vb,
                                                      float* __restrict__ S) {
    int h = blockIdx.x % NHEAD;
    int c = blockIdx.x / NHEAD;
    __shared__ ushort_t Kt[64 * 72];   // [d][l]
    __shared__ ushort_t Vt[64 * 72];   // [e][l]
    int tid = threadIdx.x;
    const size_t hb = (size_t)h * DHEAD;
#pragma unroll
    for (int it = 0; it < 4; it++) {
        int r = it * 16 + (tid >> 4);      // sequence pos within chunk
        int cc = (tid & 15) * 4;           // d/e base
        int lg = c * 64 + r;
        ushort_t kt4[4], vt4[4];
        *(uint2*)kt4 = *(const uint2*)&kf[(size_t)lg * DMODEL + hb + cc];
        *(uint2*)vt4 = *(const uint2*)&vb[(size_t)lg * DMODEL + hb + cc];
#pragma unroll
        for (int i2 = 0; i2 < 4; i2++) {
            Kt[(cc + i2) * 72 + r] = kt4[i2];
            Vt[(cc + i2) * 72 + r] = vt4[i2];
        }
    }
    __syncthreads();
    int wave = tid >> 6, lane = tid & 63, quad = lane >> 4, l16 = lane & 15;
    int wm = wave * 16;                    // d strip
    float4v acc[4];
#pragma unroll
    for (int jt = 0; jt < 4; jt++)
#pragma unroll
        for (int r = 0; r < 4; r++) acc[jt][r] = 0.0f;
#pragma unroll
    for (int ks = 0; ks < 2; ks++) {
        short8 af = *(const short8*)&Kt[(wm + l16) * 72 + ks * 32 + quad * 8];
#pragma unroll
        for (int jt = 0; jt < 4; jt++) {
            short8 bf = *(const short8*)&Vt[(jt * 16 + l16) * 72 + ks * 32 + quad * 8];
            acc[jt] = __builtin_amdgcn_mfma_f32_16x16x32_bf16(af, bf, acc[jt], 0, 0, 0);
        }
    }
    float* Sp = S + (size_t)(h * NCHUNK + c) * 4160;
#pragma unroll
    for (int jt = 0; jt < 4; jt++) {
        float4 o;
        o.x = acc[jt][0]; o.y = acc[jt][1]; o.z = acc[jt][2]; o.w = acc[jt][3];
        *(float4*)&Sp[(jt * 16 + l16) * 64 + wm + quad * 4] = o;
    }
    if (tid < 64) {
        float s = 0.f;
#pragma unroll
        for (int g = 0; g < 8; g++) {
            short8 kv8 = *(const short8*)&Kt[tid * 72 + g * 8];
#pragma unroll
            for (int i2 = 0; i2 < 8; i2++) s += b2f(((ushort_t*)&kv8)[i2]);
        }
        Sp[4096 + tid] = s;
    }
}

// ---------------- per-(head,chunk) output via MFMA; prefix computed in-block from S ----------------
// XCD-banded block swizzle: each XCD reads only ~1.5 heads' S (~1MB) -> L2-resident re-reads.
__global__ __launch_bounds__(256) void attn_out_mfma(const ushort_t* __restrict__ qf,
                                                     const ushort_t* __restrict__ kf,
                                                     const ushort_t* __restrict__ vb,
                                                     const float* __restrict__ S,
                                                     ushort_t* __restrict__ attn) {
    int bid = blockIdx.x;                 // 0..383
    int xcd = bid & 7, slot = bid >> 3;   // 48 slots per XCD
    int tile = xcd * 48 + slot;           // ordered h*32+c
    int h = tile >> 5;
    int c = tile & 31;
    __shared__ ushort_t Qs[64 * 72];   // [l][d]
    __shared__ ushort_t Ks[64 * 72];   // [j][d]
    __shared__ ushort_t Pt[64 * 72];   // [e][d]
    __shared__ ushort_t Vt[64 * 72];   // [e][j]
    __shared__ float Sc[64 * 68];      // raw scores [l][j]
    __shared__ float kpl[64];
    __shared__ float denp[4][64];
    __shared__ float dnl[64];
    int tid = threadIdx.x;
    const size_t hb = (size_t)h * DHEAD;
#pragma unroll
    for (int it = 0; it < 2; it++) {
        int chunk = it * 256 + tid;          // 0..511
        int r = chunk >> 3, c8 = (chunk & 7) * 8;
        int lg = c * 64 + r;
        *(uint4*)&Qs[r * 72 + c8] = *(const uint4*)&qf[(size_t)lg * DMODEL + hb + c8];
        *(uint4*)&Ks[r * 72 + c8] = *(const uint4*)&kf[(size_t)lg * DMODEL + hb + c8];
    }
#pragma unroll
    for (int it = 0; it < 4; it++) {
        int r = it * 16 + (tid >> 4);
        int cc = (tid & 15) * 4;
        int lg = c * 64 + r;
        ushort_t vt4[4];
        *(uint2*)vt4 = *(const uint2*)&vb[(size_t)lg * DMODEL + hb + cc];
#pragma unroll
        for (int i2 = 0; i2 < 4; i2++) Vt[(cc + i2) * 72 + r] = vt4[i2];
    }
    // in-block exclusive prefix: P = sum_{c2<c} S[h][c2] (coalesced float4 reads, L2-hot)
    {
        float4 pacc[4];
#pragma unroll
        for (int j = 0; j < 4; j++) { pacc[j].x = 0.f; pacc[j].y = 0.f; pacc[j].z = 0.f; pacc[j].w = 0.f; }
        float kpacc = 0.f;
        const float* Sh = S + (size_t)h * NCHUNK * 4160;
        for (int c2 = 0; c2 < c; c2++) {
            const float* Sp = Sh + (size_t)c2 * 4160;
#pragma unroll
            for (int j = 0; j < 4; j++) {
                float4 v4 = *(const float4*)&Sp[j * 1024 + tid * 4];
                pacc[j].x += v4.x; pacc[j].y += v4.y; pacc[j].z += v4.z; pacc[j].w += v4.w;
            }
            if (tid < 64) kpacc += Sp[4096 + tid];
        }
#pragma unroll
        for (int j = 0; j < 4; j++) {
            int i = j * 1024 + tid * 4;
            int e = i >> 6, d = i & 63;
            ushort_t o4[4];
            o4[0] = f2b(pacc[j].x); o4[1] = f2b(pacc[j].y);
            o4[2] = f2b(pacc[j].z); o4[3] = f2b(pacc[j].w);
            *(uint2*)&Pt[e * 72 + d] = *(uint2*)o4;
        }
        if (tid < 64) kpl[tid] = kpacc;
    }
    __syncthreads();
    int wave = tid >> 6, lane = tid & 63, quad = lane >> 4, l16 = lane & 15;
    int wm = wave * 16;                      // l strip
    float4v s_acc[4], n_acc[4];
#pragma unroll
    for (int jt = 0; jt < 4; jt++)
#pragma unroll
        for (int r = 0; r < 4; r++) { s_acc[jt][r] = 0.0f; n_acc[jt][r] = 0.0f; }
#pragma unroll
    for (int ks = 0; ks < 2; ks++) {
        short8 aq = *(const short8*)&Qs[(wm + l16) * 72 + ks * 32 + quad * 8];
#pragma unroll
        for (int jt = 0; jt < 4; jt++) {
            short8 bk = *(const short8*)&Ks[(jt * 16 + l16) * 72 + ks * 32 + quad * 8];
            short8 bp = *(const short8*)&Pt[(jt * 16 + l16) * 72 + ks * 32 + quad * 8];
            s_acc[jt] = __builtin_amdgcn_mfma_f32_16x16x32_bf16(aq, bk, s_acc[jt], 0, 0, 0);
            n_acc[jt] = __builtin_amdgcn_mfma_f32_16x16x32_bf16(aq, bp, n_acc[jt], 0, 0, 0);
        }
    }
#pragma unroll
    for (int jt = 0; jt < 4; jt++)
#pragma unroll
        for (int r = 0; r < 4; r++)
            Sc[(wm + quad * 4 + r) * 68 + jt * 16 + l16] = s_acc[jt][r];
    __syncthreads();
    {
        int l = tid & 63, part = tid >> 6;
        float s = 0.f;
#pragma unroll
        for (int jj = 0; jj < 16; jj++) {
            int j = part * 16 + jj;
            float v = Sc[l * 68 + j];
            s += (j <= l) ? v : 0.f;
        }
#pragma unroll
        for (int dd = 0; dd < 16; dd++) {
            int d = part * 16 + dd;
            s += b2f(Qs[l * 72 + d]) * kpl[d];
        }
        denp[part][l] = s;
    }
    __syncthreads();
    if (tid < 64) dnl[tid] = denp[0][tid] + denp[1][tid] + denp[2][tid] + denp[3][tid] + 1e-6f;
    __syncthreads();
#pragma unroll
    for (int ks = 0; ks < 2; ks++) {
        int m = wm + l16;
        float sv[8];
        *(float4*)&sv[0] = *(const float4*)&Sc[m * 68 + ks * 32 + quad * 8];
        *(float4*)&sv[4] = *(const float4*)&Sc[m * 68 + ks * 32 + quad * 8 + 4];
        ushort_t am[8];
#pragma unroll
        for (int i2 = 0; i2 < 8; i2++) {
            int j = ks * 32 + quad * 8 + i2;
            am[i2] = (j <= m) ? f2b(sv[i2]) : (ushort_t)0;
        }
        short8 af = *(short8*)am;
#pragma unroll
        for (int jt = 0; jt < 4; jt++) {
            short8 bv = *(const short8*)&Vt[(jt * 16 + l16) * 72 + ks * 32 + quad * 8];
            n_acc[jt] = __builtin_amdgcn_mfma_f32_16x16x32_bf16(af, bv, n_acc[jt], 0, 0, 0);
        }
    }
#pragma unroll
    for (int jt = 0; jt < 4; jt++) {
        int e = jt * 16 + l16;
#pragma unroll
        for (int r = 0; r < 4; r++) {
            int l = wm + quad * 4 + r;
            float o = n_acc[jt][r] / dnl[l];
            attn[(size_t)(c * 64 + l) * DMODEL + hb + e] = f2b(o);
        }
    }
}

extern "C" void kernel_launch(void* const* d_in, const int* in_sizes, int n_in,
                              void* d_out, int out_size, void* d_ws, size_t ws_size,
                              hipStream_t stream) {
    const float* x      = (const float*)d_in[0];
    const float* W_qkv  = (const float*)d_in[1];
    const float* b_qkv  = (const float*)d_in[2];
    const float* W_sem  = (const float*)d_in[3];
    const float* b_sem  = (const float*)d_in[4];
    const float* W_ctx  = (const float*)d_in[5];
    const float* b_ctx  = (const float*)d_in[6];
    const float* W_proj = (const float*)d_in[7];
    const float* b_proj = (const float*)d_in[8];
    const float* ln_g   = (const float*)d_in[9];
    const float* ln_b   = (const float*)d_in[10];
    float* out = (float*)d_out;
    float* ws  = (float*)d_ws;

    // ---- workspace (float-slot offsets); ws = 256 MiB. All regions disjoint — no overlays.
    ushort_t* Wt_merged = (ushort_t*)(ws);                 // [0, 2064384)
    ushort_t* Wt_proj   = (ushort_t*)(ws + 2064384);       // [2064384, 2359296)
    ushort_t* xb        = (ushort_t*)(ws + 2359296);       // [2359296, 3145728)
    ushort_t* xnb       = (ushort_t*)(ws + 3145728);       // [3145728, 3932160)
    ushort_t* qscb      = (ushort_t*)(ws + 3932160);       // [3932160, 9437184)
    ushort_t* qf        = (ushort_t*)(ws + 9437184);       // [9437184, 10223616)
    ushort_t* kf        = (ushort_t*)(ws + 10223616);      // [10223616, 11010048)
    float*    S         = ws + 11010048;                   // [11010048, 12607488)
    ushort_t* attnb     = (ushort_t*)(ws + 12607488);      // [12607488, 13393920)
    ushort_t* vb        = (ushort_t*)(ws + 14942208);      // [14942208, 15728640)

    pre_kernel<<<2048 + 72 * 24 * 4, 256, 0, stream>>>(x, ln_g, ln_b, xnb, xb,
                                                       W_qkv, W_sem, W_ctx, Wt_merged,
                                                       W_proj, Wt_proj);

    gemm_merged_kernel<<<672, 256, 0, stream>>>(
        xnb, xb, Wt_merged, b_qkv, b_sem, b_ctx, qscb, vb);

    gate_feat_kernel<<<(LSEQ * DMODEL / 4) / 256, 256, 0, stream>>>(qscb, qf, kf);
    chunk_sum_mfma<<<NHEAD * NCHUNK, 256, 0, stream>>>(kf, vb, S);
    attn_out_mfma<<<NHEAD * NCHUNK, 256, 0, stream>>>(qf, kf, vb, S, attnb);

    gemm_64_kernel<<<dim3(768 / 64, LSEQ / 64), 256, 0, stream>>>(attnb, Wt_proj, b_proj, out, 768, 768);
}

// Round 16
// 160.473 us; speedup vs baseline: 1.0304x; 1.0304x over previous
//
#include <hip/hip_runtime.h>
#include <math.h>

#define LSEQ 2048
#define DMODEL 768
#define NHEAD 12
#define DHEAD 64
#define NCHUNK 32   // 2048 / 64
#define NMERGED 5376   // 2304 qkv | 1536(hole: V->vb) | sem_amp sem_phase ctx_amp ctx_phase

typedef unsigned short ushort_t;
typedef __attribute__((ext_vector_type(8))) short short8;
typedef float float4v __attribute__((ext_vector_type(4)));

__device__ __forceinline__ ushort_t f2b(float f) {
    union { float f; unsigned int u; } v; v.f = f;
    unsigned int u = v.u;
    return (ushort_t)((u + 0x7fffu + ((u >> 16) & 1u)) >> 16);
}
__device__ __forceinline__ float b2f(ushort_t u) {
    union { unsigned int u; float f; } v; v.u = ((unsigned int)u) << 16;
    return v.f;
}

// async 16B global->LDS (wave-uniform LDS base + lane*16)
__device__ __forceinline__ void gl_lds16(const ushort_t* g, ushort_t* l) {
    __builtin_amdgcn_global_load_lds(
        (const __attribute__((address_space(1))) unsigned int*)g,
        (__attribute__((address_space(3))) unsigned int*)l, 16, 0, 0);
}

// ---------------- fused pre-pass: LN(+x cast) for blocks <2048, vectorized weight transpose after ----------------
__global__ void pre_kernel(const float* __restrict__ x, const float* __restrict__ g,
                           const float* __restrict__ beta, ushort_t* __restrict__ xn,
                           ushort_t* __restrict__ xb,
                           const float* __restrict__ Wq, const float* __restrict__ Ws,
                           const float* __restrict__ Wc, ushort_t* __restrict__ Tm,
                           const float* __restrict__ Wp, ushort_t* __restrict__ Tp) {
    __shared__ float red[4];
    __shared__ float bc;
    __shared__ float tile[32][33];
    int tid = threadIdx.x;
    if (blockIdx.x < 2048) {
        int row = blockIdx.x;
        const float* xr = x + (size_t)row * DMODEL;
        float v0 = xr[tid], v1 = xr[tid + 256], v2 = xr[tid + 512];
        float s = v0 + v1 + v2;
#pragma unroll
        for (int o = 32; o > 0; o >>= 1) s += __shfl_down(s, o);
        if ((tid & 63) == 0) red[tid >> 6] = s;
        __syncthreads();
        if (tid == 0) bc = (red[0] + red[1] + red[2] + red[3]) * (1.0f / DMODEL);
        __syncthreads();
        float mu = bc;
        float d0 = v0 - mu, d1 = v1 - mu, d2 = v2 - mu;
        float vs = d0 * d0 + d1 * d1 + d2 * d2;
        __syncthreads();
#pragma unroll
        for (int o = 32; o > 0; o >>= 1) vs += __shfl_down(vs, o);
        if ((tid & 63) == 0) red[tid >> 6] = vs;
        __syncthreads();
        if (tid == 0) bc = rsqrtf((red[0] + red[1] + red[2] + red[3]) * (1.0f / DMODEL) + 1e-5f);
        __syncthreads();
        float r = bc;
        ushort_t* xo = xn + (size_t)row * DMODEL;
        ushort_t* xc = xb + (size_t)row * DMODEL;
        xo[tid]       = f2b(d0 * r * g[tid]       + beta[tid]);
        xo[tid + 256] = f2b(d1 * r * g[tid + 256] + beta[tid + 256]);
        xo[tid + 512] = f2b(d2 * r * g[tid + 512] + beta[tid + 512]);
        xc[tid]       = f2b(v0);
        xc[tid + 256] = f2b(v1);
        xc[tid + 512] = f2b(v2);
    } else {
        int bid = blockIdx.x - 2048;          // 0..6911 = 72*24*4
        int nb = bid % 72;
        int kb = (bid / 72) % 24;
        int zb = bid / (72 * 24);
        const float* W; ushort_t* Wt; int N;
        switch (zb) {
            case 0: W = Wq; Wt = Tm;                        N = 2304; break;
            case 1: W = Ws; Wt = Tm + (size_t)2304 * 768;   N = 1536; break;
            case 2: W = Wc; Wt = Tm + (size_t)3840 * 768;   N = 1536; break;
            default: W = Wp; Wt = Tp;                       N = 768;  break;
        }
        int nbase = nb * 32;
        if (nbase >= N) return;
        int kbase = kb * 32;
        int tr = tid >> 3;             // 0..31
        int tc4 = (tid & 7) * 4;       // 0,4,..,28
        // load: row kbase+tr, cols nbase+tc4..+3 (float4)
        float4 wv = *(const float4*)&W[(size_t)(kbase + tr) * N + nbase + tc4];
        tile[tr][tc4 + 0] = wv.x; tile[tr][tc4 + 1] = wv.y;
        tile[tr][tc4 + 2] = wv.z; tile[tr][tc4 + 3] = wv.w;
        __syncthreads();
        // write: n-row nbase+tr, k cols kbase+tc4..+3 (4 bf16 = uint2)
        ushort_t o4[4];
        o4[0] = f2b(tile[tc4 + 0][tr]); o4[1] = f2b(tile[tc4 + 1][tr]);
        o4[2] = f2b(tile[tc4 + 2][tr]); o4[3] = f2b(tile[tc4 + 3][tr]);
        *(uint2*)&Wt[(size_t)(nbase + tr) * 768 + kbase + tc4] = *(uint2*)o4;
    }
}

// ---------------- merged bf16 MFMA GEMM: BK=32 single-buffer, swizzled LDS, XCD-banded grid,
//                  LDS-staged coalesced bf16 epilogue (R12 proven) ----------------
__global__ __launch_bounds__(256) void gemm_merged_kernel(
    const ushort_t* __restrict__ Axn, const ushort_t* __restrict__ Axb,
    const ushort_t* __restrict__ Bt,
    const float* __restrict__ b_qkv, const float* __restrict__ b_sem,
    const float* __restrict__ b_ctx, ushort_t* __restrict__ Cb,
    ushort_t* __restrict__ vb) {
    const int K = 768;
    __shared__ ushort_t As[128 * 32];
    __shared__ ushort_t Bs[128 * 32];
    __shared__ ushort_t Ct[128 * 132];   // padded stride: coalescing stage for C
    int tid = threadIdx.x;
    int wave = tid >> 6, lane = tid & 63;
    int wm = (wave >> 1) * 64, wn = (wave & 1) * 64;
    int quad = lane >> 4, l16 = lane & 15;
    int bid = blockIdx.x;                 // 0..671
    int xcd = bid & 7, slot = bid >> 3;   // 84 slots per XCD
    int tile_id = xcd * 84 + slot;
    int m0 = (tile_id & 15) * 128;        // m fastest: 16 consecutive slots share one B tile
    int n0 = (tile_id >> 4) * 128;
    const ushort_t* A = (n0 < 2304) ? Axn : Axb;
    const float* bias = (n0 < 2304) ? (b_qkv + n0) : (n0 < 3840 ? (b_sem + n0 - 2304) : (b_ctx + n0 - 3840));

    int r0 = tid >> 2;                                  // row 0..63 (both 64-row halves)
    int kc = ((tid & 3) ^ ((r0 >> 1) & 3)) * 8;         // swizzled global k-chunk
    const ushort_t* Ag0 = A + (size_t)(m0 + r0) * K + kc;
    const ushort_t* Ag1 = A + (size_t)(m0 + 64 + r0) * K + kc;
    const ushort_t* Bg0 = Bt + (size_t)(n0 + r0) * K + kc;
    const ushort_t* Bg1 = Bt + (size_t)(n0 + 64 + r0) * K + kc;
    ushort_t* Al0 = &As[(wave * 64) * 8];
    ushort_t* Al1 = &As[(256 + wave * 64) * 8];
    ushort_t* Bl0 = &Bs[(wave * 64) * 8];
    ushort_t* Bl1 = &Bs[(256 + wave * 64) * 8];

    float4v acc[4][4];
#pragma unroll
    for (int i = 0; i < 4; i++)
#pragma unroll
        for (int j = 0; j < 4; j++)
#pragma unroll
            for (int r = 0; r < 4; r++) acc[i][j][r] = 0.0f;

    for (int k0 = 0; k0 < K; k0 += 32) {
        gl_lds16(Ag0 + k0, Al0);
        gl_lds16(Ag1 + k0, Al1);
        gl_lds16(Bg0 + k0, Bl0);
        gl_lds16(Bg1 + k0, Bl1);
        __syncthreads();
        short8 af[4], bf[4];
#pragma unroll
        for (int i = 0; i < 4; i++) {
            int rr = wm + i * 16 + l16;
            af[i] = *(const short8*)&As[rr * 32 + ((quad ^ ((rr >> 1) & 3)) * 8)];
        }
#pragma unroll
        for (int j = 0; j < 4; j++) {
            int rr = wn + j * 16 + l16;
            bf[j] = *(const short8*)&Bs[rr * 32 + ((quad ^ ((rr >> 1) & 3)) * 8)];
        }
#pragma unroll
        for (int i = 0; i < 4; i++)
#pragma unroll
            for (int j = 0; j < 4; j++)
                acc[i][j] = __builtin_amdgcn_mfma_f32_16x16x32_bf16(af[i], bf[j], acc[i][j], 0, 0, 0);
        __syncthreads();
    }
    // epilogue: acc -> bf16 LDS tile, then coalesced 16B stores
#pragma unroll
    for (int i = 0; i < 4; i++) {
#pragma unroll
        for (int j = 0; j < 4; j++) {
            int colb = wn + j * 16 + l16;
            float bv = bias[colb];
#pragma unroll
            for (int r = 0; r < 4; r++) {
                int row = wm + i * 16 + quad * 4 + r;
                Ct[row * 132 + colb] = f2b(acc[i][j][r] + bv);
            }
        }
    }
    __syncthreads();
    bool is_v = (n0 >= 1536 && n0 < 2304);   // block-uniform
    int rr0 = tid >> 4;             // 0..15
    int cc0 = (tid & 15) * 8;       // 0..120
#pragma unroll
    for (int p = 0; p < 8; p++) {
        int r = p * 16 + rr0;
        uint4 vdat = *(const uint4*)&Ct[r * 132 + cc0];
        int grow = m0 + r;
        if (is_v) {
            *(uint4*)&vb[(size_t)grow * DMODEL + (n0 - 1536) + cc0] = vdat;
        } else {
            *(uint4*)&Cb[(size_t)grow * NMERGED + n0 + cc0] = vdat;
        }
    }
}

// ---------------- 64x64-tile bf16 MFMA GEMM, BK=32, swizzled (proj: N=768), fp32 out ----------------
__global__ __launch_bounds__(256) void gemm_64_kernel(
    const ushort_t* __restrict__ A, const ushort_t* __restrict__ Bt,
    const float* __restrict__ bias, float* __restrict__ C,
    int N, int K) {
    __shared__ ushort_t As[64 * 32];
    __shared__ ushort_t Bs[64 * 32];
    int tid = threadIdx.x;
    int wave = tid >> 6, lane = tid & 63;
    int wm = (wave >> 1) * 32, wn = (wave & 1) * 32;
    int quad = lane >> 4, l16 = lane & 15;
    int m0 = blockIdx.y * 64, n0 = blockIdx.x * 64;

    int r0 = tid >> 2;
    int kc = ((tid & 3) ^ ((r0 >> 1) & 3)) * 8;
    const ushort_t* Ag = A + (size_t)(m0 + r0) * K + kc;
    const ushort_t* Bg = Bt + (size_t)(n0 + r0) * K + kc;
    ushort_t* Al = &As[(wave * 16) * 32];
    ushort_t* Bl = &Bs[(wave * 16) * 32];

    float4v acc[2][2];
#pragma unroll
    for (int i = 0; i < 2; i++)
#pragma unroll
        for (int j = 0; j < 2; j++)
#pragma unroll
            for (int r = 0; r < 4; r++) acc[i][j][r] = 0.0f;

    for (int k0 = 0; k0 < K; k0 += 32) {
        gl_lds16(Ag + k0, Al);
        gl_lds16(Bg + k0, Bl);
        __syncthreads();
        short8 af[2], bf[2];
#pragma unroll
        for (int i = 0; i < 2; i++) {
            int rr = wm + i * 16 + l16;
            af[i] = *(const short8*)&As[rr * 32 + ((quad ^ ((rr >> 1) & 3)) * 8)];
        }
#pragma unroll
        for (int j = 0; j < 2; j++) {
            int rr = wn + j * 16 + l16;
            bf[j] = *(const short8*)&Bs[rr * 32 + ((quad ^ ((rr >> 1) & 3)) * 8)];
        }
#pragma unroll
        for (int i = 0; i < 2; i++)
#pragma unroll
            for (int j = 0; j < 2; j++)
                acc[i][j] = __builtin_amdgcn_mfma_f32_16x16x32_bf16(af[i], bf[j], acc[i][j], 0, 0, 0);
        __syncthreads();
    }
#pragma unroll
    for (int i = 0; i < 2; i++) {
#pragma unroll
        for (int j = 0; j < 2; j++) {
            int col = n0 + wn + j * 16 + l16;
            float bv = bias[col];
#pragma unroll
            for (int r = 0; r < 4; r++) {
                int row = m0 + wm + i * 16 + quad * 4 + r;
                C[(size_t)row * N + col] = acc[i][j][r] + bv;
            }
        }
    }
}

// ---------------- gate + feature map (bf16 in) -> bf16 qf/kf (8 elems/thread, uint4 streams) ----------------
__device__ __forceinline__ float softplus_f(float x) {
    return (x > 15.f) ? x : log1pf(expf(x));
}

__global__ void gate_feat_kernel(const ushort_t* __restrict__ qscb,
                                 ushort_t* __restrict__ qf, ushort_t* __restrict__ kf) {
    int t = blockIdx.x * 256 + threadIdx.x;      // t < L*D/8 = 196608
    int l = t / 96, d = (t - l * 96) * 8;
    size_t base = (size_t)l * NMERGED;
    ushort_t sa[8], sp[8], ca[8], cp[8], q[8], k[8];
    *(uint4*)sa = *(const uint4*)&qscb[base + 2304 + d];
    *(uint4*)sp = *(const uint4*)&qscb[base + 3072 + d];
    *(uint4*)ca = *(const uint4*)&qscb[base + 3840 + d];
    *(uint4*)cp = *(const uint4*)&qscb[base + 4608 + d];
    *(uint4*)q  = *(const uint4*)&qscb[base + d];
    *(uint4*)k  = *(const uint4*)&qscb[base + 768 + d];
    ushort_t qo[8], ko[8];
#pragma unroll
    for (int j = 0; j < 8; j++) {
        float amp = softplus_f(b2f(sa[j])) * softplus_f(b2f(ca[j]));
        float tt = amp * cosf(b2f(sp[j]) - b2f(cp[j]));
        float gate = 1.0f / (1.0f + expf(-tt));
        float kv = b2f(k[j]) * gate;
        float qv = b2f(q[j]);
        qo[j] = f2b((qv > 0.f) ? qv + 1.0f : expf(qv));
        ko[j] = f2b((kv > 0.f) ? kv + 1.0f : expf(kv));
    }
    size_t o = (size_t)l * DMODEL + d;
    *(uint4*)&qf[o] = *(uint4*)qo;
    *(uint4*)&kf[o] = *(uint4*)ko;
}

// ---------------- per-(head,chunk) KV state sums via MFMA (R12 proven) ----------------
// S_t layout per (h,c): [e*64+d] = sum_l k[l][d]*v[l][e]; [4096+d] = ksum[d]
__global__ __launch_bounds__(256) void chunk_sum_mfma(const ushort_t* __restrict__ kf,
                                                      const ushort_t* __restrict__ vb,
                                                      float* __restrict__ S) {
    int h = blockIdx.x % NHEAD;
    int c = blockIdx.x / NHEAD;
    __shared__ ushort_t Kt[64 * 72];   // [d][l]
    __shared__ ushort_t Vt[64 * 72];   // [e][l]
    int tid = threadIdx.x;
    const size_t hb = (size_t)h * DHEAD;
#pragma unroll
    for (int it = 0; it < 4; it++) {
        int r = it * 16 + (tid >> 4);      // sequence pos within chunk
        int cc = (tid & 15) * 4;           // d/e base
        int lg = c * 64 + r;
        ushort_t kt4[4], vt4[4];
        *(uint2*)kt4 = *(const uint2*)&kf[(size_t)lg * DMODEL + hb + cc];
        *(uint2*)vt4 = *(const uint2*)&vb[(size_t)lg * DMODEL + hb + cc];
#pragma unroll
        for (int i2 = 0; i2 < 4; i2++) {
            Kt[(cc + i2) * 72 + r] = kt4[i2];
            Vt[(cc + i2) * 72 + r] = vt4[i2];
        }
    }
    __syncthreads();
    int wave = tid >> 6, lane = tid & 63, quad = lane >> 4, l16 = lane & 15;
    int wm = wave * 16;                    // d strip
    float4v acc[4];
#pragma unroll
    for (int jt = 0; jt < 4; jt++)
#pragma unroll
        for (int r = 0; r < 4; r++) acc[jt][r] = 0.0f;
#pragma unroll
    for (int ks = 0; ks < 2; ks++) {
        short8 af = *(const short8*)&Kt[(wm + l16) * 72 + ks * 32 + quad * 8];
#pragma unroll
        for (int jt = 0; jt < 4; jt++) {
            short8 bf = *(const short8*)&Vt[(jt * 16 + l16) * 72 + ks * 32 + quad * 8];
            acc[jt] = __builtin_amdgcn_mfma_f32_16x16x32_bf16(af, bf, acc[jt], 0, 0, 0);
        }
    }
    float* Sp = S + (size_t)(h * NCHUNK + c) * 4160;
#pragma unroll
    for (int jt = 0; jt < 4; jt++) {
        float4 o;
        o.x = acc[jt][0]; o.y = acc[jt][1]; o.z = acc[jt][2]; o.w = acc[jt][3];
        *(float4*)&Sp[(jt * 16 + l16) * 64 + wm + quad * 4] = o;
    }
    if (tid < 64) {
        float s = 0.f;
#pragma unroll
        for (int g = 0; g < 8; g++) {
            short8 kv8 = *(const short8*)&Kt[tid * 72 + g * 8];
#pragma unroll
            for (int i2 = 0; i2 < 8; i2++) s += b2f(((ushort_t*)&kv8)[i2]);
        }
        Sp[4096 + tid] = s;
    }
}

// ---------------- exclusive prefix over chunks: S_t -> Pb (bf16 [e][d]) + kpf (f32) ----------------
__global__ void prefix_kernel(const float* __restrict__ S, ushort_t* __restrict__ Pb,
                              float* __restrict__ kpf) {
    int h = blockIdx.x;
    int i = blockIdx.y * 256 + threadIdx.x;
    if (i >= 4160) return;
    float v[NCHUNK];
    size_t base = (size_t)h * NCHUNK * 4160 + i;
#pragma unroll
    for (int c2 = 0; c2 < NCHUNK; c2++) v[c2] = S[base + (size_t)c2 * 4160];
    float run = 0.f;
    if (i < 4096) {
        size_t pb = (size_t)h * NCHUNK * 4096 + i;
#pragma unroll
        for (int c2 = 0; c2 < NCHUNK; c2++) {
            Pb[pb + (size_t)c2 * 4096] = f2b(run);
            run += v[c2];
        }
    } else {
        size_t kb = (size_t)h * NCHUNK * 64 + (i - 4096);
#pragma unroll
        for (int c2 = 0; c2 < NCHUNK; c2++) {
            kpf[kb + (size_t)c2 * 64] = run;
            run += v[c2];
        }
    }
}

// ---------------- per-(head,chunk) output via MFMA (R12 proven) ----------------
__global__ __launch_bounds__(256) void attn_out_mfma(const ushort_t* __restrict__ qf,
                                                     const ushort_t* __restrict__ kf,
                                                     const ushort_t* __restrict__ vb,
                                                     const ushort_t* __restrict__ Pb,
                                                     const float* __restrict__ kpf,
                                                     ushort_t* __restrict__ attn) {
    int h = blockIdx.x % NHEAD;
    int c = blockIdx.x / NHEAD;
    __shared__ ushort_t Qs[64 * 72];   // [l][d]
    __shared__ ushort_t Ks[64 * 72];   // [j][d]
    __shared__ ushort_t Pt[64 * 72];   // [e][d]
    __shared__ ushort_t Vt[64 * 72];   // [e][j]
    __shared__ float Sc[64 * 68];      // raw scores [l][j]
    __shared__ float kpl[64];
    __shared__ float denp[4][64];
    __shared__ float dnl[64];
    int tid = threadIdx.x;
    const size_t hb = (size_t)h * DHEAD;
    const size_t pcb = (size_t)(h * NCHUNK + c);
#pragma unroll
    for (int it = 0; it < 2; it++) {
        int chunk = it * 256 + tid;          // 0..511
        int r = chunk >> 3, c8 = (chunk & 7) * 8;
        int lg = c * 64 + r;
        *(uint4*)&Qs[r * 72 + c8] = *(const uint4*)&qf[(size_t)lg * DMODEL + hb + c8];
        *(uint4*)&Ks[r * 72 + c8] = *(const uint4*)&kf[(size_t)lg * DMODEL + hb + c8];
        *(uint4*)&Pt[r * 72 + c8] = *(const uint4*)&Pb[pcb * 4096 + r * 64 + c8];
    }
#pragma unroll
    for (int it = 0; it < 4; it++) {
        int r = it * 16 + (tid >> 4);
        int cc = (tid & 15) * 4;
        int lg = c * 64 + r;
        ushort_t vt4[4];
        *(uint2*)vt4 = *(const uint2*)&vb[(size_t)lg * DMODEL + hb + cc];
#pragma unroll
        for (int i2 = 0; i2 < 4; i2++) Vt[(cc + i2) * 72 + r] = vt4[i2];
    }
    if (tid < 64) kpl[tid] = kpf[pcb * 64 + tid];
    __syncthreads();
    int wave = tid >> 6, lane = tid & 63, quad = lane >> 4, l16 = lane & 15;
    int wm = wave * 16;                      // l strip
    float4v s_acc[4], n_acc[4];
#pragma unroll
    for (int jt = 0; jt < 4; jt++)
#pragma unroll
        for (int r = 0; r < 4; r++) { s_acc[jt][r] = 0.0f; n_acc[jt][r] = 0.0f; }
#pragma unroll
    for (int ks = 0; ks < 2; ks++) {
        short8 aq = *(const short8*)&Qs[(wm + l16) * 72 + ks * 32 + quad * 8];
#pragma unroll
        for (int jt = 0; jt < 4; jt++) {
            short8 bk = *(const short8*)&Ks[(jt * 16 + l16) * 72 + ks * 32 + quad * 8];
            short8 bp = *(const short8*)&Pt[(jt * 16 + l16) * 72 + ks * 32 + quad * 8];
            s_acc[jt] = __builtin_amdgcn_mfma_f32_16x16x32_bf16(aq, bk, s_acc[jt], 0, 0, 0);
            n_acc[jt] = __builtin_amdgcn_mfma_f32_16x16x32_bf16(aq, bp, n_acc[jt], 0, 0, 0);
        }
    }
#pragma unroll
    for (int jt = 0; jt < 4; jt++)
#pragma unroll
        for (int r = 0; r < 4; r++)
            Sc[(wm + quad * 4 + r) * 68 + jt * 16 + l16] = s_acc[jt][r];
    __syncthreads();
    {
        int l = tid & 63, part = tid >> 6;
        float s = 0.f;
#pragma unroll
        for (int jj = 0; jj < 16; jj++) {
            int j = part * 16 + jj;
            float v = Sc[l * 68 + j];
            s += (j <= l) ? v : 0.f;
        }
#pragma unroll
        for (int dd = 0; dd < 16; dd++) {
            int d = part * 16 + dd;
            s += b2f(Qs[l * 72 + d]) * kpl[d];
        }
        denp[part][l] = s;
    }
    __syncthreads();
    if (tid < 64) dnl[tid] = denp[0][tid] + denp[1][tid] + denp[2][tid] + denp[3][tid] + 1e-6f;
    __syncthreads();
#pragma unroll
    for (int ks = 0; ks < 2; ks++) {
        int m = wm + l16;
        float sv[8];
        *(float4*)&sv[0] = *(const float4*)&Sc[m * 68 + ks * 32 + quad * 8];
        *(float4*)&sv[4] = *(const float4*)&Sc[m * 68 + ks * 32 + quad * 8 + 4];
        ushort_t am[8];
#pragma unroll
        for (int i2 = 0; i2 < 8; i2++) {
            int j = ks * 32 + quad * 8 + i2;
            am[i2] = (j <= m) ? f2b(sv[i2]) : (ushort_t)0;
        }
        short8 af = *(short8*)am;
#pragma unroll
        for (int jt = 0; jt < 4; jt++) {
            short8 bv = *(const short8*)&Vt[(jt * 16 + l16) * 72 + ks * 32 + quad * 8];
            n_acc[jt] = __builtin_amdgcn_mfma_f32_16x16x32_bf16(af, bv, n_acc[jt], 0, 0, 0);
        }
    }
#pragma unroll
    for (int jt = 0; jt < 4; jt++) {
        int e = jt * 16 + l16;
#pragma unroll
        for (int r = 0; r < 4; r++) {
            int l = wm + quad * 4 + r;
            float o = n_acc[jt][r] / dnl[l];
            attn[(size_t)(c * 64 + l) * DMODEL + hb + e] = f2b(o);
        }
    }
}

extern "C" void kernel_launch(void* const* d_in, const int* in_sizes, int n_in,
                              void* d_out, int out_size, void* d_ws, size_t ws_size,
                              hipStream_t stream) {
    const float* x      = (const float*)d_in[0];
    const float* W_qkv  = (const float*)d_in[1];
    const float* b_qkv  = (const float*)d_in[2];
    const float* W_sem  = (const float*)d_in[3];
    const float* b_sem  = (const float*)d_in[4];
    const float* W_ctx  = (const float*)d_in[5];
    const float* b_ctx  = (const float*)d_in[6];
    const float* W_proj = (const float*)d_in[7];
    const float* b_proj = (const float*)d_in[8];
    const float* ln_g   = (const float*)d_in[9];
    const float* ln_b   = (const float*)d_in[10];
    float* out = (float*)d_out;
    float* ws  = (float*)d_ws;

    // ---- workspace (float-slot offsets); ws = 256 MiB. All regions disjoint — no overlays.
    ushort_t* Wt_merged = (ushort_t*)(ws);                 // [0, 2064384)
    ushort_t* Wt_proj   = (ushort_t*)(ws + 2064384);       // [2064384, 2359296)
    ushort_t* xb        = (ushort_t*)(ws + 2359296);       // [2359296, 3145728)
    ushort_t* xnb       = (ushort_t*)(ws + 3145728);       // [3145728, 3932160)
    ushort_t* qscb      = (ushort_t*)(ws + 3932160);       // [3932160, 9437184)
    ushort_t* qf        = (ushort_t*)(ws + 9437184);       // [9437184, 10223616)
    ushort_t* kf        = (ushort_t*)(ws + 10223616);      // [10223616, 11010048)
    float*    S         = ws + 11010048;                   // [11010048, 12607488)
    ushort_t* attnb     = (ushort_t*)(ws + 12607488);      // [12607488, 13393920)
    ushort_t* vb        = (ushort_t*)(ws + 14942208);      // [14942208, 15728640)
    ushort_t* Pb        = (ushort_t*)(ws + 16777216);      // [16777216, 17563648)
    float*    kpf       = ws + 17563648;                   // [17563648, 17588224)

    pre_kernel<<<2048 + 72 * 24 * 4, 256, 0, stream>>>(x, ln_g, ln_b, xnb, xb,
                                                       W_qkv, W_sem, W_ctx, Wt_merged,
                                                       W_proj, Wt_proj);

    gemm_merged_kernel<<<672, 256, 0, stream>>>(
        xnb, xb, Wt_merged, b_qkv, b_sem, b_ctx, qscb, vb);

    gate_feat_kernel<<<(LSEQ * DMODEL / 8) / 256, 256, 0, stream>>>(qscb, qf, kf);
    chunk_sum_mfma<<<NHEAD * NCHUNK, 256, 0, stream>>>(kf, vb, S);
    prefix_kernel<<<dim3(NHEAD, 17), 256, 0, stream>>>(S, Pb, kpf);
    attn_out_mfma<<<NHEAD * NCHUNK, 256, 0, stream>>>(qf, kf, vb, Pb, kpf, attnb);

    gemm_64_kernel<<<dim3(768 / 64, LSEQ / 64), 256, 0, stream>>>(attnb, Wt_proj, b_proj, out, 768, 768);
}

// Round 17
// 156.406 us; speedup vs baseline: 1.0572x; 1.0260x over previous
//
#include <hip/hip_runtime.h>
#include <math.h>

#define LSEQ 2048
#define DMODEL 768
#define NHEAD 12
#define DHEAD 64
#define NCHUNK 32   // 2048 / 64
#define NMERGED 5376   // 2304 qkv | 1536(hole: V->vb) | sem_amp sem_phase ctx_amp ctx_phase

typedef unsigned short ushort_t;
typedef __attribute__((ext_vector_type(8))) short short8;
typedef float float4v __attribute__((ext_vector_type(4)));

__device__ __forceinline__ ushort_t f2b(float f) {
    union { float f; unsigned int u; } v; v.f = f;
    unsigned int u = v.u;
    return (ushort_t)((u + 0x7fffu + ((u >> 16) & 1u)) >> 16);
}
__device__ __forceinline__ float b2f(ushort_t u) {
    union { unsigned int u; float f; } v; v.u = ((unsigned int)u) << 16;
    return v.f;
}

// async 16B global->LDS (wave-uniform LDS base + lane*16)
__device__ __forceinline__ void gl_lds16(const ushort_t* g, ushort_t* l) {
    __builtin_amdgcn_global_load_lds(
        (const __attribute__((address_space(1))) unsigned int*)g,
        (__attribute__((address_space(3))) unsigned int*)l, 16, 0, 0);
}

// ---------------- fused pre-pass: LN(+x cast) for blocks <2048, weight transpose after ----------------
__global__ void pre_kernel(const float* __restrict__ x, const float* __restrict__ g,
                           const float* __restrict__ beta, ushort_t* __restrict__ xn,
                           ushort_t* __restrict__ xb,
                           const float* __restrict__ Wq, const float* __restrict__ Ws,
                           const float* __restrict__ Wc, ushort_t* __restrict__ Tm,
                           const float* __restrict__ Wp, ushort_t* __restrict__ Tp) {
    __shared__ float red[4];
    __shared__ float bc;
    __shared__ float tile[32][33];
    int tid = threadIdx.x;
    if (blockIdx.x < 2048) {
        int row = blockIdx.x;
        const float* xr = x + (size_t)row * DMODEL;
        float v0 = xr[tid], v1 = xr[tid + 256], v2 = xr[tid + 512];
        float s = v0 + v1 + v2;
#pragma unroll
        for (int o = 32; o > 0; o >>= 1) s += __shfl_down(s, o);
        if ((tid & 63) == 0) red[tid >> 6] = s;
        __syncthreads();
        if (tid == 0) bc = (red[0] + red[1] + red[2] + red[3]) * (1.0f / DMODEL);
        __syncthreads();
        float mu = bc;
        float d0 = v0 - mu, d1 = v1 - mu, d2 = v2 - mu;
        float vs = d0 * d0 + d1 * d1 + d2 * d2;
        __syncthreads();
#pragma unroll
        for (int o = 32; o > 0; o >>= 1) vs += __shfl_down(vs, o);
        if ((tid & 63) == 0) red[tid >> 6] = vs;
        __syncthreads();
        if (tid == 0) bc = rsqrtf((red[0] + red[1] + red[2] + red[3]) * (1.0f / DMODEL) + 1e-5f);
        __syncthreads();
        float r = bc;
        ushort_t* xo = xn + (size_t)row * DMODEL;
        ushort_t* xc = xb + (size_t)row * DMODEL;
        xo[tid]       = f2b(d0 * r * g[tid]       + beta[tid]);
        xo[tid + 256] = f2b(d1 * r * g[tid + 256] + beta[tid + 256]);
        xo[tid + 512] = f2b(d2 * r * g[tid + 512] + beta[tid + 512]);
        xc[tid]       = f2b(v0);
        xc[tid + 256] = f2b(v1);
        xc[tid + 512] = f2b(v2);
    } else {
        int bid = blockIdx.x - 2048;          // 0..6911 = 72*24*4
        int nb = bid % 72;
        int kb = (bid / 72) % 24;
        int zb = bid / (72 * 24);
        const float* W; ushort_t* Wt; int N;
        switch (zb) {
            case 0: W = Wq; Wt = Tm;                        N = 2304; break;
            case 1: W = Ws; Wt = Tm + (size_t)2304 * 768;   N = 1536; break;
            case 2: W = Wc; Wt = Tm + (size_t)3840 * 768;   N = 1536; break;
            default: W = Wp; Wt = Tp;                       N = 768;  break;
        }
        int nbase = nb * 32;
        if (nbase >= N) return;
        int tr = tid >> 5, tc = tid & 31;
        int kbase = kb * 32;
#pragma unroll
        for (int p = 0; p < 4; p++) {
            int r = p * 8 + tr;
            tile[r][tc] = W[(size_t)(kbase + r) * N + nbase + tc];
        }
        __syncthreads();
#pragma unroll
        for (int p = 0; p < 4; p++) {
            int r = p * 8 + tr;
            Wt[(size_t)(nbase + r) * 768 + kbase + tc] = f2b(tile[tc][r]);
        }
    }
}

// ---------------- merged bf16 MFMA GEMM: BK=32 single-buffer, swizzled LDS, XCD-banded grid,
//                  LDS-staged coalesced bf16 epilogue (R12 proven) ----------------
__global__ __launch_bounds__(256) void gemm_merged_kernel(
    const ushort_t* __restrict__ Axn, const ushort_t* __restrict__ Axb,
    const ushort_t* __restrict__ Bt,
    const float* __restrict__ b_qkv, const float* __restrict__ b_sem,
    const float* __restrict__ b_ctx, ushort_t* __restrict__ Cb,
    ushort_t* __restrict__ vb) {
    const int K = 768;
    __shared__ ushort_t As[128 * 32];
    __shared__ ushort_t Bs[128 * 32];
    __shared__ ushort_t Ct[128 * 132];   // padded stride: coalescing stage for C
    int tid = threadIdx.x;
    int wave = tid >> 6, lane = tid & 63;
    int wm = (wave >> 1) * 64, wn = (wave & 1) * 64;
    int quad = lane >> 4, l16 = lane & 15;
    int bid = blockIdx.x;                 // 0..671
    int xcd = bid & 7, slot = bid >> 3;   // 84 slots per XCD
    int tile_id = xcd * 84 + slot;
    int m0 = (tile_id & 15) * 128;        // m fastest: 16 consecutive slots share one B tile
    int n0 = (tile_id >> 4) * 128;
    const ushort_t* A = (n0 < 2304) ? Axn : Axb;
    const float* bias = (n0 < 2304) ? (b_qkv + n0) : (n0 < 3840 ? (b_sem + n0 - 2304) : (b_ctx + n0 - 3840));

    int r0 = tid >> 2;                                  // row 0..63 (both 64-row halves)
    int kc = ((tid & 3) ^ ((r0 >> 1) & 3)) * 8;         // swizzled global k-chunk
    const ushort_t* Ag0 = A + (size_t)(m0 + r0) * K + kc;
    const ushort_t* Ag1 = A + (size_t)(m0 + 64 + r0) * K + kc;
    const ushort_t* Bg0 = Bt + (size_t)(n0 + r0) * K + kc;
    const ushort_t* Bg1 = Bt + (size_t)(n0 + 64 + r0) * K + kc;
    ushort_t* Al0 = &As[(wave * 64) * 8];
    ushort_t* Al1 = &As[(256 + wave * 64) * 8];
    ushort_t* Bl0 = &Bs[(wave * 64) * 8];
    ushort_t* Bl1 = &Bs[(256 + wave * 64) * 8];

    float4v acc[4][4];
#pragma unroll
    for (int i = 0; i < 4; i++)
#pragma unroll
        for (int j = 0; j < 4; j++)
#pragma unroll
            for (int r = 0; r < 4; r++) acc[i][j][r] = 0.0f;

    for (int k0 = 0; k0 < K; k0 += 32) {
        gl_lds16(Ag0 + k0, Al0);
        gl_lds16(Ag1 + k0, Al1);
        gl_lds16(Bg0 + k0, Bl0);
        gl_lds16(Bg1 + k0, Bl1);
        __syncthreads();
        short8 af[4], bf[4];
#pragma unroll
        for (int i = 0; i < 4; i++) {
            int rr = wm + i * 16 + l16;
            af[i] = *(const short8*)&As[rr * 32 + ((quad ^ ((rr >> 1) & 3)) * 8)];
        }
#pragma unroll
        for (int j = 0; j < 4; j++) {
            int rr = wn + j * 16 + l16;
            bf[j] = *(const short8*)&Bs[rr * 32 + ((quad ^ ((rr >> 1) & 3)) * 8)];
        }
#pragma unroll
        for (int i = 0; i < 4; i++)
#pragma unroll
            for (int j = 0; j < 4; j++)
                acc[i][j] = __builtin_amdgcn_mfma_f32_16x16x32_bf16(af[i], bf[j], acc[i][j], 0, 0, 0);
        __syncthreads();
    }
    // epilogue: acc -> bf16 LDS tile, then coalesced 16B stores
#pragma unroll
    for (int i = 0; i < 4; i++) {
#pragma unroll
        for (int j = 0; j < 4; j++) {
            int colb = wn + j * 16 + l16;
            float bv = bias[colb];
#pragma unroll
            for (int r = 0; r < 4; r++) {
                int row = wm + i * 16 + quad * 4 + r;
                Ct[row * 132 + colb] = f2b(acc[i][j][r] + bv);
            }
        }
    }
    __syncthreads();
    bool is_v = (n0 >= 1536 && n0 < 2304);   // block-uniform
    int rr0 = tid >> 4;             // 0..15
    int cc0 = (tid & 15) * 8;       // 0..120
#pragma unroll
    for (int p = 0; p < 8; p++) {
        int r = p * 16 + rr0;
        uint4 vdat = *(const uint4*)&Ct[r * 132 + cc0];
        int grow = m0 + r;
        if (is_v) {
            *(uint4*)&vb[(size_t)grow * DMODEL + (n0 - 1536) + cc0] = vdat;
        } else {
            *(uint4*)&Cb[(size_t)grow * NMERGED + n0 + cc0] = vdat;
        }
    }
}

// ---------------- 64x64-tile bf16 MFMA GEMM, BK=32, swizzled (proj: N=768), fp32 out ----------------
__global__ __launch_bounds__(256) void gemm_64_kernel(
    const ushort_t* __restrict__ A, const ushort_t* __restrict__ Bt,
    const float* __restrict__ bias, float* __restrict__ C,
    int N, int K) {
    __shared__ ushort_t As[64 * 32];
    __shared__ ushort_t Bs[64 * 32];
    int tid = threadIdx.x;
    int wave = tid >> 6, lane = tid & 63;
    int wm = (wave >> 1) * 32, wn = (wave & 1) * 32;
    int quad = lane >> 4, l16 = lane & 15;
    int m0 = blockIdx.y * 64, n0 = blockIdx.x * 64;

    int r0 = tid >> 2;
    int kc = ((tid & 3) ^ ((r0 >> 1) & 3)) * 8;
    const ushort_t* Ag = A + (size_t)(m0 + r0) * K + kc;
    const ushort_t* Bg = Bt + (size_t)(n0 + r0) * K + kc;
    ushort_t* Al = &As[(wave * 16) * 32];
    ushort_t* Bl = &Bs[(wave * 16) * 32];

    float4v acc[2][2];
#pragma unroll
    for (int i = 0; i < 2; i++)
#pragma unroll
        for (int j = 0; j < 2; j++)
#pragma unroll
            for (int r = 0; r < 4; r++) acc[i][j][r] = 0.0f;

    for (int k0 = 0; k0 < K; k0 += 32) {
        gl_lds16(Ag + k0, Al);
        gl_lds16(Bg + k0, Bl);
        __syncthreads();
        short8 af[2], bf[2];
#pragma unroll
        for (int i = 0; i < 2; i++) {
            int rr = wm + i * 16 + l16;
            af[i] = *(const short8*)&As[rr * 32 + ((quad ^ ((rr >> 1) & 3)) * 8)];
        }
#pragma unroll
        for (int j = 0; j < 2; j++) {
            int rr = wn + j * 16 + l16;
            bf[j] = *(const short8*)&Bs[rr * 32 + ((quad ^ ((rr >> 1) & 3)) * 8)];
        }
#pragma unroll
        for (int i = 0; i < 2; i++)
#pragma unroll
            for (int j = 0; j < 2; j++)
                acc[i][j] = __builtin_amdgcn_mfma_f32_16x16x32_bf16(af[i], bf[j], acc[i][j], 0, 0, 0);
        __syncthreads();
    }
#pragma unroll
    for (int i = 0; i < 2; i++) {
#pragma unroll
        for (int j = 0; j < 2; j++) {
            int col = n0 + wn + j * 16 + l16;
            float bv = bias[col];
#pragma unroll
            for (int r = 0; r < 4; r++) {
                int row = m0 + wm + i * 16 + quad * 4 + r;
                C[(size_t)row * N + col] = acc[i][j][r] + bv;
            }
        }
    }
}

// ---------------- gate + feature map (bf16 in) -> bf16 qf/kf (4 elems/thread) ----------------
__device__ __forceinline__ float softplus_f(float x) {
    return (x > 15.f) ? x : log1pf(expf(x));
}

__global__ void gate_feat_kernel(const ushort_t* __restrict__ qscb,
                                 ushort_t* __restrict__ qf, ushort_t* __restrict__ kf) {
    int t = blockIdx.x * 256 + threadIdx.x;      // t < L*D/4 = 393216
    int l = t / 192, d = (t - l * 192) * 4;
    size_t base = (size_t)l * NMERGED;
    ushort_t sa[4], sp[4], ca[4], cp[4], q[4], k[4];
    *(uint2*)sa = *(const uint2*)&qscb[base + 2304 + d];
    *(uint2*)sp = *(const uint2*)&qscb[base + 3072 + d];
    *(uint2*)ca = *(const uint2*)&qscb[base + 3840 + d];
    *(uint2*)cp = *(const uint2*)&qscb[base + 4608 + d];
    *(uint2*)q  = *(const uint2*)&qscb[base + d];
    *(uint2*)k  = *(const uint2*)&qscb[base + 768 + d];
    ushort_t qo[4], ko[4];
#pragma unroll
    for (int j = 0; j < 4; j++) {
        float amp = softplus_f(b2f(sa[j])) * softplus_f(b2f(ca[j]));
        float tt = amp * cosf(b2f(sp[j]) - b2f(cp[j]));
        float gate = 1.0f / (1.0f + expf(-tt));
        float kv = b2f(k[j]) * gate;
        float qv = b2f(q[j]);
        qo[j] = f2b((qv > 0.f) ? qv + 1.0f : expf(qv));
        ko[j] = f2b((kv > 0.f) ? kv + 1.0f : expf(kv));
    }
    size_t o = (size_t)l * DMODEL + d;
    *(uint2*)&qf[o] = *(uint2*)qo;
    *(uint2*)&kf[o] = *(uint2*)ko;
}

// ---------------- per-(head,chunk) KV state sums via MFMA ----------------
// S_t layout per (h,c): [e*64+d] = sum_l k[l][d]*v[l][e]; [4096+d] = ksum[d]
__global__ __launch_bounds__(256) void chunk_sum_mfma(const ushort_t* __restrict__ kf,
                                                      const ushort_t* __restrict__ vb,
                                                      float* __restrict__ S) {
    int h = blockIdx.x % NHEAD;
    int c = blockIdx.x / NHEAD;
    __shared__ ushort_t Kt[64 * 72];   // [d][l]
    __shared__ ushort_t Vt[64 * 72];   // [e][l]
    int tid = threadIdx.x;
    const size_t hb = (size_t)h * DHEAD;
#pragma unroll
    for (int it = 0; it < 4; it++) {
        int r = it * 16 + (tid >> 4);      // sequence pos within chunk
        int cc = (tid & 15) * 4;           // d/e base
        int lg = c * 64 + r;
        ushort_t kt4[4], vt4[4];
        *(uint2*)kt4 = *(const uint2*)&kf[(size_t)lg * DMODEL + hb + cc];
        *(uint2*)vt4 = *(const uint2*)&vb[(size_t)lg * DMODEL + hb + cc];
#pragma unroll
        for (int i2 = 0; i2 < 4; i2++) {
            Kt[(cc + i2) * 72 + r] = kt4[i2];
            Vt[(cc + i2) * 72 + r] = vt4[i2];
        }
    }
    __syncthreads();
    int wave = tid >> 6, lane = tid & 63, quad = lane >> 4, l16 = lane & 15;
    int wm = wave * 16;                    // d strip
    float4v acc[4];
#pragma unroll
    for (int jt = 0; jt < 4; jt++)
#pragma unroll
        for (int r = 0; r < 4; r++) acc[jt][r] = 0.0f;
#pragma unroll
    for (int ks = 0; ks < 2; ks++) {
        short8 af = *(const short8*)&Kt[(wm + l16) * 72 + ks * 32 + quad * 8];
#pragma unroll
        for (int jt = 0; jt < 4; jt++) {
            short8 bf = *(const short8*)&Vt[(jt * 16 + l16) * 72 + ks * 32 + quad * 8];
            acc[jt] = __builtin_amdgcn_mfma_f32_16x16x32_bf16(af, bf, acc[jt], 0, 0, 0);
        }
    }
    float* Sp = S + (size_t)(h * NCHUNK + c) * 4160;
#pragma unroll
    for (int jt = 0; jt < 4; jt++) {
        float4 o;
        o.x = acc[jt][0]; o.y = acc[jt][1]; o.z = acc[jt][2]; o.w = acc[jt][3];
        *(float4*)&Sp[(jt * 16 + l16) * 64 + wm + quad * 4] = o;
    }
    if (tid < 64) {
        float s = 0.f;
#pragma unroll
        for (int g = 0; g < 8; g++) {
            short8 kv8 = *(const short8*)&Kt[tid * 72 + g * 8];
#pragma unroll
            for (int i2 = 0; i2 < 8; i2++) s += b2f(((ushort_t*)&kv8)[i2]);
        }
        Sp[4096 + tid] = s;
    }
}

// ---------------- exclusive prefix over chunks: S_t -> Pb (bf16 [e][d]) + kpf (f32) ----------------
__global__ void prefix_kernel(const float* __restrict__ S, ushort_t* __restrict__ Pb,
                              float* __restrict__ kpf) {
    int h = blockIdx.x;
    int i = blockIdx.y * 256 + threadIdx.x;
    if (i >= 4160) return;
    float v[NCHUNK];
    size_t base = (size_t)h * NCHUNK * 4160 + i;
#pragma unroll
    for (int c2 = 0; c2 < NCHUNK; c2++) v[c2] = S[base + (size_t)c2 * 4160];
    float run = 0.f;
    if (i < 4096) {
        size_t pb = (size_t)h * NCHUNK * 4096 + i;
#pragma unroll
        for (int c2 = 0; c2 < NCHUNK; c2++) {
            Pb[pb + (size_t)c2 * 4096] = f2b(run);
            run += v[c2];
        }
    } else {
        size_t kb = (size_t)h * NCHUNK * 64 + (i - 4096);
#pragma unroll
        for (int c2 = 0; c2 < NCHUNK; c2++) {
            kpf[kb + (size_t)c2 * 64] = run;
            run += v[c2];
        }
    }
}

// ---------------- per-(head,chunk) output via MFMA ----------------
__global__ __launch_bounds__(256) void attn_out_mfma(const ushort_t* __restrict__ qf,
                                                     const ushort_t* __restrict__ kf,
                                                     const ushort_t* __restrict__ vb,
                                                     const ushort_t* __restrict__ Pb,
                                                     const float* __restrict__ kpf,
                                                     ushort_t* __restrict__ attn) {
    int h = blockIdx.x % NHEAD;
    int c = blockIdx.x / NHEAD;
    __shared__ ushort_t Qs[64 * 72];   // [l][d]
    __shared__ ushort_t Ks[64 * 72];   // [j][d]
    __shared__ ushort_t Pt[64 * 72];   // [e][d]
    __shared__ ushort_t Vt[64 * 72];   // [e][j]
    __shared__ float Sc[64 * 68];      // raw scores [l][j]
    __shared__ float kpl[64];
    __shared__ float denp[4][64];
    __shared__ float dnl[64];
    int tid = threadIdx.x;
    const size_t hb = (size_t)h * DHEAD;
    const size_t pcb = (size_t)(h * NCHUNK + c);
#pragma unroll
    for (int it = 0; it < 2; it++) {
        int chunk = it * 256 + tid;          // 0..511
        int r = chunk >> 3, c8 = (chunk & 7) * 8;
        int lg = c * 64 + r;
        *(uint4*)&Qs[r * 72 + c8] = *(const uint4*)&qf[(size_t)lg * DMODEL + hb + c8];
        *(uint4*)&Ks[r * 72 + c8] = *(const uint4*)&kf[(size_t)lg * DMODEL + hb + c8];
        *(uint4*)&Pt[r * 72 + c8] = *(const uint4*)&Pb[pcb * 4096 + r * 64 + c8];
    }
#pragma unroll
    for (int it = 0; it < 4; it++) {
        int r = it * 16 + (tid >> 4);
        int cc = (tid & 15) * 4;
        int lg = c * 64 + r;
        ushort_t vt4[4];
        *(uint2*)vt4 = *(const uint2*)&vb[(size_t)lg * DMODEL + hb + cc];
#pragma unroll
        for (int i2 = 0; i2 < 4; i2++) Vt[(cc + i2) * 72 + r] = vt4[i2];
    }
    if (tid < 64) kpl[tid] = kpf[pcb * 64 + tid];
    __syncthreads();
    int wave = tid >> 6, lane = tid & 63, quad = lane >> 4, l16 = lane & 15;
    int wm = wave * 16;                      // l strip
    float4v s_acc[4], n_acc[4];
#pragma unroll
    for (int jt = 0; jt < 4; jt++)
#pragma unroll
        for (int r = 0; r < 4; r++) { s_acc[jt][r] = 0.0f; n_acc[jt][r] = 0.0f; }
#pragma unroll
    for (int ks = 0; ks < 2; ks++) {
        short8 aq = *(const short8*)&Qs[(wm + l16) * 72 + ks * 32 + quad * 8];
#pragma unroll
        for (int jt = 0; jt < 4; jt++) {
            short8 bk = *(const short8*)&Ks[(jt * 16 + l16) * 72 + ks * 32 + quad * 8];
            short8 bp = *(const short8*)&Pt[(jt * 16 + l16) * 72 + ks * 32 + quad * 8];
            s_acc[jt] = __builtin_amdgcn_mfma_f32_16x16x32_bf16(aq, bk, s_acc[jt], 0, 0, 0);
            n_acc[jt] = __builtin_amdgcn_mfma_f32_16x16x32_bf16(aq, bp, n_acc[jt], 0, 0, 0);
        }
    }
#pragma unroll
    for (int jt = 0; jt < 4; jt++)
#pragma unroll
        for (int r = 0; r < 4; r++)
            Sc[(wm + quad * 4 + r) * 68 + jt * 16 + l16] = s_acc[jt][r];
    __syncthreads();
    {
        int l = tid & 63, part = tid >> 6;
        float s = 0.f;
#pragma unroll
        for (int jj = 0; jj < 16; jj++) {
            int j = part * 16 + jj;
            float v = Sc[l * 68 + j];
            s += (j <= l) ? v : 0.f;
        }
#pragma unroll
        for (int dd = 0; dd < 16; dd++) {
            int d = part * 16 + dd;
            s += b2f(Qs[l * 72 + d]) * kpl[d];
        }
        denp[part][l] = s;
    }
    __syncthreads();
    if (tid < 64) dnl[tid] = denp[0][tid] + denp[1][tid] + denp[2][tid] + denp[3][tid] + 1e-6f;
    __syncthreads();
#pragma unroll
    for (int ks = 0; ks < 2; ks++) {
        int m = wm + l16;
        float sv[8];
        *(float4*)&sv[0] = *(const float4*)&Sc[m * 68 + ks * 32 + quad * 8];
        *(float4*)&sv[4] = *(const float4*)&Sc[m * 68 + ks * 32 + quad * 8 + 4];
        ushort_t am[8];
#pragma unroll
        for (int i2 = 0; i2 < 8; i2++) {
            int j = ks * 32 + quad * 8 + i2;
            am[i2] = (j <= m) ? f2b(sv[i2]) : (ushort_t)0;
        }
        short8 af = *(short8*)am;
#pragma unroll
        for (int jt = 0; jt < 4; jt++) {
            short8 bv = *(const short8*)&Vt[(jt * 16 + l16) * 72 + ks * 32 + quad * 8];
            n_acc[jt] = __builtin_amdgcn_mfma_f32_16x16x32_bf16(af, bv, n_acc[jt], 0, 0, 0);
        }
    }
#pragma unroll
    for (int jt = 0; jt < 4; jt++) {
        int e = jt * 16 + l16;
#pragma unroll
        for (int r = 0; r < 4; r++) {
            int l = wm + quad * 4 + r;
            float o = n_acc[jt][r] / dnl[l];
            attn[(size_t)(c * 64 + l) * DMODEL + hb + e] = f2b(o);
        }
    }
}

extern "C" void kernel_launch(void* const* d_in, const int* in_sizes, int n_in,
                              void* d_out, int out_size, void* d_ws, size_t ws_size,
                              hipStream_t stream) {
    const float* x      = (const float*)d_in[0];
    const float* W_qkv  = (const float*)d_in[1];
    const float* b_qkv  = (const float*)d_in[2];
    const float* W_sem  = (const float*)d_in[3];
    const float* b_sem  = (const float*)d_in[4];
    const float* W_ctx  = (const float*)d_in[5];
    const float* b_ctx  = (const float*)d_in[6];
    const float* W_proj = (const float*)d_in[7];
    const float* b_proj = (const float*)d_in[8];
    const float* ln_g   = (const float*)d_in[9];
    const float* ln_b   = (const float*)d_in[10];
    float* out = (float*)d_out;
    float* ws  = (float*)d_ws;

    // ---- workspace (float-slot offsets); ws = 256 MiB. All regions disjoint — no overlays.
    ushort_t* Wt_merged = (ushort_t*)(ws);                 // [0, 2064384)
    ushort_t* Wt_proj   = (ushort_t*)(ws + 2064384);       // [2064384, 2359296)
    ushort_t* xb        = (ushort_t*)(ws + 2359296);       // [2359296, 3145728)
    ushort_t* xnb       = (ushort_t*)(ws + 3145728);       // [3145728, 3932160)
    ushort_t* qscb      = (ushort_t*)(ws + 3932160);       // [3932160, 9437184)
    ushort_t* qf        = (ushort_t*)(ws + 9437184);       // [9437184, 10223616)
    ushort_t* kf        = (ushort_t*)(ws + 10223616);      // [10223616, 11010048)
    float*    S         = ws + 11010048;                   // [11010048, 12607488)
    ushort_t* attnb     = (ushort_t*)(ws + 12607488);      // [12607488, 13393920)
    ushort_t* vb        = (ushort_t*)(ws + 14942208);      // [14942208, 15728640)
    ushort_t* Pb        = (ushort_t*)(ws + 16777216);      // [16777216, 17563648)
    float*    kpf       = ws + 17563648;                   // [17563648, 17588224)

    pre_kernel<<<2048 + 72 * 24 * 4, 256, 0, stream>>>(x, ln_g, ln_b, xnb, xb,
                                                       W_qkv, W_sem, W_ctx, Wt_merged,
                                                       W_proj, Wt_proj);

    gemm_merged_kernel<<<672, 256, 0, stream>>>(
        xnb, xb, Wt_merged, b_qkv, b_sem, b_ctx, qscb, vb);

    gate_feat_kernel<<<(LSEQ * DMODEL / 4) / 256, 256, 0, stream>>>(qscb, qf, kf);
    chunk_sum_mfma<<<NHEAD * NCHUNK, 256, 0, stream>>>(kf, vb, S);
    prefix_kernel<<<dim3(NHEAD, 17), 256, 0, stream>>>(S, Pb, kpf);
    attn_out_mfma<<<NHEAD * NCHUNK, 256, 0, stream>>>(qf, kf, vb, Pb, kpf, attnb);

    gemm_64_kernel<<<dim3(768 / 64, LSEQ / 64), 256, 0, stream>>>(attnb, Wt_proj, b_proj, out, 768, 768);
}